// Round 17
// baseline (381.892 us; speedup 1.0000x reference)
//
#include <hip/hip_runtime.h>
#include <hip/hip_bf16.h>

// CornerPool on MI355X, round 19: byte-identical resubmission of round 18
// (pod died transport-level BEFORE kernel push -- "first message" failure on
// the same flaky pod that killed kernels of every sync structure while
// identical resubmissions succeeded). r18 = 2-blocks/CU conv3x3 with the
// granule-rotation fix: stage rotation (gq - ((idx>>1)&3))&3 is the exact
// inverse of read rotation (q + ((idx>>1)&3))&3 (r15-proven algebra).
// Structure: 256-thread blocks, tile 2 rows x 128 w x 128 co, LDS 57.9KB ->
// 2 resident blocks/CU, chunk = 3 dw-group phases (syncthreads only),
// XCD-decorrelated stagger (bx>>3)%NCH. Inter-block overlap (m114) hides
// one block's stage phase under the other block's tap phases.

using bf16x8  = __attribute__((ext_vector_type(8))) __bf16;
using floatx4 = __attribute__((ext_vector_type(4))) float;

typedef __attribute__((address_space(1))) const uint32_t gas_u32;
typedef __attribute__((address_space(3))) uint32_t las_u32;

__device__ __forceinline__ float bf2f(__hip_bfloat16 h) { return __bfloat162float(h); }
__device__ __forceinline__ __hip_bfloat16 f2bf(float f) { return __float2bfloat16(f); }

// ---------------- prep kernels ----------------

// x: [8][256][128][128] fp32 NCHW -> xb: [8][128][128][256] bf16 NHWC
__global__ __launch_bounds__(256) void k_cast_x(const float* __restrict__ x,
                                                __hip_bfloat16* __restrict__ xb) {
    __shared__ float t[64][65];
    const int n  = blockIdx.z;
    const int h  = blockIdx.y;
    const int c0 = (blockIdx.x >> 1) * 64;
    const int w0 = (blockIdx.x & 1) * 64;
    const int tid = threadIdx.x;
#pragma unroll
    for (int it = 0; it < 16; ++it) {
        int idx = it * 256 + tid;
        int c = idx >> 6, w = idx & 63;
        t[c][w] = x[(((size_t)n * 256 + c0 + c) * 128 + h) * 128 + w0 + w];
    }
    __syncthreads();
#pragma unroll
    for (int it = 0; it < 16; ++it) {
        int idx = it * 256 + tid;
        int w = idx >> 6, c = idx & 63;
        xb[(((size_t)n * 128 + h) * 128 + w0 + w) * 256 + c0 + c] = f2bf(t[c][w]);
    }
}

// bn params [4][C] -> scale[C], bias[C]
__global__ void k_prep_bn(const float* __restrict__ p, float* __restrict__ sc,
                          float* __restrict__ bi, int C) {
    int i = blockIdx.x * 64 + threadIdx.x;
    if (i >= C) return;
    float g = p[i], b = p[C + i], m = p[2 * C + i], v = p[3 * C + i];
    float s = g / sqrtf(v + 1e-5f);
    sc[i] = s;
    bi[i] = b - m * s;
}

// 3x3: src fp32 [CoS][Cin][3][3] -> dst bf16 [tap][Cin/32][CoutTot][32] at co_off
__global__ void k_reorder_w3(const float* __restrict__ src, __hip_bfloat16* __restrict__ dst,
                             const float* __restrict__ scale, int Cin, int CoutTot,
                             int co_off, int total) {
    int i = blockIdx.x * 256 + threadIdx.x;
    if (i >= total) return;
    int ci  = i % Cin;
    int tap = (i / Cin) % 9;
    int co  = i / (Cin * 9);
    dst[((((size_t)tap * (Cin >> 5) + (ci >> 5)) * CoutTot) + co_off + co) * 32 + (ci & 31)] =
        f2bf(src[((size_t)co * Cin + ci) * 9 + tap] * scale[co]);
}

// 1x1: src fp32 [Co][Cin] -> dst bf16 [Co][Cin], scaled
__global__ void k_reorder_w1(const float* __restrict__ src, __hip_bfloat16* __restrict__ dst,
                             const float* __restrict__ scale, int Cin, int total) {
    int i = blockIdx.x * 256 + threadIdx.x;
    if (i >= total) return;
    dst[i] = f2bf(src[i] * scale[i / Cin]);
}

// ---------------- pools (NHWC bf16, C=64, in-place) ----------------

__global__ __launch_bounds__(256) void k_pool1(__hip_bfloat16* __restrict__ b) {
    const int idx = blockIdx.x * 256 + threadIdx.x; // 8*128*64 = 65536
    const int c = idx & 63;
    const int w = (idx >> 6) & 127;
    const int n = idx >> 13;
    const size_t stride = 128 * 64;
    const size_t base = ((size_t)n * 128 * 128 + w) * 64 + c;
    float m = 0.0f; // post-relu inputs are >= 0
    for (int hb = 31; hb >= 0; --hb) {
        size_t a0 = base + (size_t)(4 * hb) * stride;
        float v0 = bf2f(b[a0]);
        float v1 = bf2f(b[a0 + stride]);
        float v2 = bf2f(b[a0 + 2 * stride]);
        float v3 = bf2f(b[a0 + 3 * stride]);
        float m3 = fmaxf(m, v3);
        float m2 = fmaxf(m3, v2);
        float m1 = fmaxf(m2, v1);
        float m0 = fmaxf(m1, v0);
        b[a0 + 3 * stride] = f2bf(m3);
        b[a0 + 2 * stride] = f2bf(m2);
        b[a0 + stride]     = f2bf(m1);
        b[a0]              = f2bf(m0);
        m = m0;
    }
}

__global__ __launch_bounds__(256) void k_pool2(__hip_bfloat16* __restrict__ b,
                                               const __hip_bfloat16* __restrict__ pl) {
    const int idx = blockIdx.x * 256 + threadIdx.x;
    const int c = idx & 63;
    const int h = (idx >> 6) & 127;
    const int n = idx >> 13;
    const size_t base = (((size_t)n * 128 + h) * 128) * 64 + c;
    float m = 0.0f;
    for (int wb = 31; wb >= 0; --wb) {
        size_t a0 = base + (size_t)(4 * wb) * 64;
        float v0 = bf2f(b[a0]);
        float v1 = bf2f(b[a0 + 64]);
        float v2 = bf2f(b[a0 + 128]);
        float v3 = bf2f(b[a0 + 192]);
        float u0 = bf2f(pl[a0]);
        float u1 = bf2f(pl[a0 + 64]);
        float u2 = bf2f(pl[a0 + 128]);
        float u3 = bf2f(pl[a0 + 192]);
        float m3 = fmaxf(m, v3);
        float m2 = fmaxf(m3, v2);
        float m1 = fmaxf(m2, v1);
        float m0 = fmaxf(m1, v0);
        b[a0 + 192] = f2bf(m3 + u3);
        b[a0 + 128] = f2bf(m2 + u2);
        b[a0 + 64]  = f2bf(m1 + u1);
        b[a0]       = f2bf(m0 + u0);
        m = m0;
    }
}

// ---------------- 1x1 conv (res branch): GEMM 16384x256x256 ----------------
__global__ __launch_bounds__(256) void conv1x1(const __hip_bfloat16* __restrict__ xin,
                                               const __hip_bfloat16* __restrict__ wgt,
                                               const float* __restrict__ bias,
                                               __hip_bfloat16* __restrict__ out) {
    __shared__ __align__(16) __hip_bfloat16 Xs[128 * 64];
    __shared__ __align__(16) __hip_bfloat16 Ws[128 * 64];
    const int tid  = threadIdx.x;
    const int lane = tid & 63;
    const int wid  = tid >> 6;
    const int wm = wid >> 1, wn = wid & 1;
    const int p0 = blockIdx.x * 128;
    const int c0 = blockIdx.y * 128;
    const int q = lane >> 4, r16 = lane & 15;

    floatx4 acc[4][4] = {};

    for (int k0 = 0; k0 < 256; k0 += 64) {
#pragma unroll
        for (int it = 0; it < 4; ++it) {
            const int pp = it * 32 + (tid >> 3);
            const int g  = tid & 7;
            uint4 val = *(const uint4*)(xin + ((size_t)(p0 + pp) * 256 + k0 + g * 8));
            *(uint4*)(&Xs[pp * 64 + (((g + pp) & 7) * 8)]) = val;
        }
#pragma unroll
        for (int it = 0; it < 4; ++it) {
            const int rr = it * 32 + (tid >> 3);
            const int g  = tid & 7;
            uint4 val = *(const uint4*)(wgt + ((size_t)(c0 + rr) * 256 + k0 + g * 8));
            *(uint4*)(&Ws[rr * 64 + (((g + rr) & 7) * 8)]) = val;
        }
        __syncthreads();
#pragma unroll
        for (int ks = 0; ks < 2; ++ks) {
            bf16x8 afr[4], bfr[4];
#pragma unroll
            for (int i = 0; i < 4; ++i) {
                const int pp = wm * 64 + i * 16 + r16;
                const int g  = ks * 4 + q;
                afr[i] = *(const bf16x8*)(&Xs[pp * 64 + (((g + pp) & 7) * 8)]);
            }
#pragma unroll
            for (int j = 0; j < 4; ++j) {
                const int rr = wn * 64 + j * 16 + r16;
                const int g  = ks * 4 + q;
                bfr[j] = *(const bf16x8*)(&Ws[rr * 64 + (((g + rr) & 7) * 8)]);
            }
#pragma unroll
            for (int i = 0; i < 4; ++i)
#pragma unroll
                for (int j = 0; j < 4; ++j)
                    acc[i][j] = __builtin_amdgcn_mfma_f32_16x16x32_bf16(afr[i], bfr[j], acc[i][j], 0, 0, 0);
        }
        __syncthreads();
    }
#pragma unroll
    for (int j = 0; j < 4; ++j) {
        const int co = c0 + wn * 64 + j * 16 + r16;
        const float bi = bias[co];
#pragma unroll
        for (int i = 0; i < 4; ++i) {
            const int pb = p0 + wm * 64 + i * 16 + q * 4;
#pragma unroll
            for (int r = 0; r < 4; ++r)
                out[(size_t)(pb + r) * 256 + co] = f2bf(acc[i][j][r] + bi);
        }
    }
}

// ---------------- 2-rows-per-block 3x3 conv (2 blocks/CU) ----------------
// Block: 2 image rows x 128 w x 128 co. 256 threads, 4 waves
// (wm 0..1 over w, 64 each; wn 0..1 over co, 64 each). Per wave:
// acc[2 rows][4 i][4 j] = 32 frags = 128 AGPR.
// LDS: Xs[4][130][32] (33.3KB) + Ws[3][128][32] (24.6KB) = 57.9KB ->
// 2 resident blocks/CU. Chunk = 3 phases: {stageW(dwg) (+stageX at dwg0);
// __syncthreads; tapsg(dwg); __syncthreads}. Granule rotation: LDS [.][idx][gq]
// holds source group (gq - ((idx>>1)&3))&3; read pg = (q + ((idx>>1)&3))&3
// -> lane reads its own q-th ci-group (r15-verified algebra).
// MODE 1: +relu -> split bf16 NHWC out/out2 (co<64 -> out, else out2), COUT=128
// MODE 2: +bias +res, relu -> bf16 NHWC out, COUT=256
// MODE 3: +relu -> fp32 NCHW out (swapped operands, D[co][w]), COUT=256
template <int CIN, int COUT, int MODE>
__global__ __launch_bounds__(256, 2) void conv3x3(const __hip_bfloat16* __restrict__ xin,
                                                  const __hip_bfloat16* __restrict__ wgt,
                                                  const float* __restrict__ bias,
                                                  void* __restrict__ out,
                                                  const __hip_bfloat16* __restrict__ resbuf,
                                                  __hip_bfloat16* __restrict__ out2) {
    constexpr int NCH = CIN / 32;
    __shared__ __align__(16) __hip_bfloat16 Xs[4 * 130 * 32]; // 33,280 B
    __shared__ __align__(16) __hip_bfloat16 Ws[3 * 128 * 32]; // 24,576 B
    const int tid  = threadIdx.x;
    const int lane = tid & 63;
    const int wid  = tid >> 6;        // 0..3
    const int wm   = wid >> 1;        // 0..1: w-dim, 64 each
    const int wn   = wid & 1;         // 0..1: co, 64 each
    const int bx   = blockIdx.x;      // 0..511 = (n, hblock)
    const int n     = bx >> 6;        // image
    const int hbase = (bx & 63) * 2;  // first output row
    const int co_off = blockIdx.y * 128;
    const int q = lane >> 4, r16 = lane & 15;

    // staging lane decomposition (16B granules)
    const int le = lane >> 2;         // 0..15: row-slot within a gll
    const int gq = lane & 3;          // dest granule

    floatx4 acc[2][4][4] = {};

    // stage X chunk c: 4 halo rows x e=1..128 x 32 ci (32 gll, 8 per wave)
    auto stageX = [&](int c) {
        const int ci0 = c * 32;
#pragma unroll
        for (int it = 0; it < 8; ++it) {
            const int cid = it * 4 + wid;   // 0..31
            const int row = cid >> 3;       // 0..3
            const int m   = cid & 7;
            const int e0  = m * 16 + 1;     // 1,17,...,113
            const int hh  = hbase - 1 + row;
            const int e   = e0 + le;        // 1..128
            const int g   = (gq - ((e >> 1) & 3)) & 3; // inverse of read rotation
            if (0 <= hh && hh < 128) {      // wave-uniform
                const __hip_bfloat16* src =
                    xin + ((size_t)(n * 128 + hh) * 128 + (e - 1)) * CIN + ci0 + g * 8;
                __builtin_amdgcn_global_load_lds((gas_u32*)src,
                    (las_u32*)&Xs[((size_t)row * 130 + e0) * 32], 16, 0, 0);
            } else {
                *(uint4*)(&Xs[((size_t)row * 130 + e) * 32 + gq * 8]) =
                    make_uint4(0u, 0u, 0u, 0u);
            }
        }
    };
    // stage dw-group dwg of chunk c into Ws (24 gll, 6 per wave)
    auto stageW = [&](int c, int dwg) {
#pragma unroll
        for (int it = 0; it < 6; ++it) {
            const int cid  = it * 4 + wid;  // 0..23
            const int tr   = cid >> 3;      // 0..2
            const int m    = cid & 7;
            const int row0 = m * 16;        // 0..112
            const int wrow = row0 + le;
            const int g    = (gq - ((wrow >> 1) & 3)) & 3; // inverse of read rotation
            const int tap  = tr * 3 + dwg;
            const __hip_bfloat16* src =
                wgt + ((size_t)(tap * NCH + c) * COUT + co_off + wrow) * 32 + g * 8;
            __builtin_amdgcn_global_load_lds((gas_u32*)src,
                (las_u32*)&Ws[((size_t)tr * 128 + row0) * 32], 16, 0, 0);
        }
    };
    // one dw-group of taps (96 MFMA/wave)
    auto tapsg = [&](int dwg) {
        const int dw = dwg - 1;
        bf16x8 bfr[3][4];
#pragma unroll
        for (int tr = 0; tr < 3; ++tr)
#pragma unroll
            for (int j = 0; j < 4; ++j) {
                const int row = wn * 64 + j * 16 + r16;
                const int pg  = (q + ((row >> 1) & 3)) & 3;
                bfr[tr][j] = *(const bf16x8*)(&Ws[((size_t)tr * 128 + row) * 32 + pg * 8]);
            }
#pragma unroll
        for (int i = 0; i < 4; ++i) {
            const int e  = wm * 64 + i * 16 + r16 + dw + 1; // 0..129
            const int pg = (q + ((e >> 1) & 3)) & 3;
            bf16x8 afr[4];
#pragma unroll
            for (int rr = 0; rr < 4; ++rr)
                afr[rr] = *(const bf16x8*)(&Xs[((size_t)rr * 130 + e) * 32 + pg * 8]);
#pragma unroll
            for (int tr = 0; tr < 3; ++tr)
#pragma unroll
                for (int row = 0; row < 2; ++row)
#pragma unroll
                    for (int j = 0; j < 4; ++j) {
                        if (MODE == 3)
                            acc[row][i][j] = __builtin_amdgcn_mfma_f32_16x16x32_bf16(
                                bfr[tr][j], afr[row + tr], acc[row][i][j], 0, 0, 0);
                        else
                            acc[row][i][j] = __builtin_amdgcn_mfma_f32_16x16x32_bf16(
                                afr[row + tr], bfr[tr][j], acc[row][i][j], 0, 0, 0);
                    }
        }
    };

    // zero w-halo columns e=0,129 (4 rows x 2 sides x 4 granules = 32 thr)
    if (tid < 32) {
        int row = tid >> 3, side = (tid >> 2) & 1, p = tid & 3;
        *(uint4*)(&Xs[((size_t)row * 130 + (side ? 129 : 0)) * 32 + p * 8]) =
            make_uint4(0u, 0u, 0u, 0u);
    }
    // XCD-decorrelated chunk stagger (r15)
    const int off = (bx >> 3) % NCH;

    for (int c = 0; c < NCH; ++c) {
        const int cc = (c + off) % NCH;
#pragma unroll
        for (int dwg = 0; dwg < 3; ++dwg) {
            if (dwg == 0) stageX(cc);
            stageW(cc, dwg);
            __syncthreads(); // DMA drained; LDS ready (also covers halo zero)
            tapsg(dwg);
            __syncthreads(); // taps done before next overwrite
        }
    }

    if (MODE == 1) {
#pragma unroll
        for (int row = 0; row < 2; ++row) {
            const int h = hbase + row;
#pragma unroll
            for (int j = 0; j < 4; ++j) {
                const int co = wn * 64 + j * 16 + r16; // 0..127
                const float bi = bias[co];
                __hip_bfloat16* ob = (co < 64) ? (__hip_bfloat16*)out : out2;
                const int ch = co & 63;
#pragma unroll
                for (int i = 0; i < 4; ++i) {
#pragma unroll
                    for (int r = 0; r < 4; ++r) {
                        const int w = wm * 64 + i * 16 + q * 4 + r;
                        const size_t p = (size_t)(n * 128 + h) * 128 + w;
                        ob[p * 64 + ch] = f2bf(fmaxf(acc[row][i][j][r] + bi, 0.0f));
                    }
                }
            }
        }
    } else if (MODE == 2) {
        __hip_bfloat16* o = (__hip_bfloat16*)out;
#pragma unroll
        for (int row = 0; row < 2; ++row) {
            const int h = hbase + row;
#pragma unroll
            for (int j = 0; j < 4; ++j) {
                const int co = co_off + wn * 64 + j * 16 + r16;
                const float bi = bias[co];
#pragma unroll
                for (int i = 0; i < 4; ++i) {
#pragma unroll
                    for (int r = 0; r < 4; ++r) {
                        const int w = wm * 64 + i * 16 + q * 4 + r;
                        const size_t p = (size_t)(n * 128 + h) * 128 + w;
                        float v = acc[row][i][j][r] + bi + bf2f(resbuf[p * 256 + co]);
                        o[p * 256 + co] = f2bf(fmaxf(v, 0.0f));
                    }
                }
            }
        }
    } else { // MODE 3: fp32 NCHW, D[co][w] (swapped operands)
        float* o = (float*)out;
#pragma unroll
        for (int row = 0; row < 2; ++row) {
            const int h = hbase + row;
#pragma unroll
            for (int j = 0; j < 4; ++j) {
#pragma unroll
                for (int r = 0; r < 4; ++r) {
                    const int co = co_off + wn * 64 + j * 16 + q * 4 + r;
                    const float bi = bias[co];
#pragma unroll
                    for (int i = 0; i < 4; ++i) {
                        const int w = wm * 64 + i * 16 + r16;
                        float v = fmaxf(acc[row][i][j][r] + bi, 0.0f);
                        o[(((size_t)(n * 256 + co)) * 128 + h) * 128 + w] = v;
                    }
                }
            }
        }
    }
}

// ---------------- launcher ----------------

extern "C" void kernel_launch(void* const* d_in, const int* in_sizes, int n_in,
                              void* d_out, int out_size, void* d_ws, size_t ws_size,
                              hipStream_t stream) {
    const float* x       = (const float*)d_in[0];
    const float* w_res   = (const float*)d_in[1];
    const float* bn_res  = (const float*)d_in[2];
    const float* w_vpre  = (const float*)d_in[3];
    const float* bn_vpre = (const float*)d_in[4];
    const float* w_hpre  = (const float*)d_in[5];
    const float* bn_hpre = (const float*)d_in[6];
    const float* w_add   = (const float*)d_in[7];
    const float* bn_add  = (const float*)d_in[8];
    const float* w_post  = (const float*)d_in[9];
    const float* bn_post = (const float*)d_in[10];

    const size_t SZ_XB = (size_t)8 * 128 * 128 * 256 * 2; // 67,108,864
    const size_t SZ_P  = (size_t)8 * 128 * 128 * 64 * 2;  // 16,777,216

    char* w = (char*)d_ws;
    __hip_bfloat16* xb   = (__hip_bfloat16*)(w);          // reused as add-conv output
    __hip_bfloat16* resb = (__hip_bfloat16*)(w + SZ_XB);
    __hip_bfloat16* p1   = (__hip_bfloat16*)(w + 2 * SZ_XB);
    __hip_bfloat16* p2   = (__hip_bfloat16*)(w + 2 * SZ_XB + SZ_P);
    char* wp = w + 2 * SZ_XB + 2 * SZ_P;
    __hip_bfloat16* wres  = (__hip_bfloat16*)wp; wp += (size_t)65536 * 2;        // [256][256]
    __hip_bfloat16* wpre  = (__hip_bfloat16*)wp; wp += (size_t)9 * 128 * 256 * 2; // [9][8][128][32]
    __hip_bfloat16* wadd  = (__hip_bfloat16*)wp; wp += (size_t)9 * 256 * 64 * 2;  // [9][2][256][32]
    __hip_bfloat16* wpost = (__hip_bfloat16*)wp; wp += (size_t)9 * 256 * 256 * 2; // [9][8][256][32]
    float* sc_res  = (float*)wp; wp += 256 * 4;
    float* bi_res  = (float*)wp; wp += 256 * 4;
    float* sc_pre  = (float*)wp; wp += 128 * 4;
    float* bi_pre  = (float*)wp; wp += 128 * 4;
    float* sc_add  = (float*)wp; wp += 256 * 4;
    float* bi_add  = (float*)wp; wp += 256 * 4;
    float* sc_post = (float*)wp; wp += 256 * 4;
    float* bi_post = (float*)wp; wp += 256 * 4;

    // BN prep first (reorder kernels consume the scales)
    k_prep_bn<<<4, 64, 0, stream>>>(bn_res, sc_res, bi_res, 256);
    k_prep_bn<<<1, 64, 0, stream>>>(bn_vpre, sc_pre, bi_pre, 64);
    k_prep_bn<<<1, 64, 0, stream>>>(bn_hpre, sc_pre + 64, bi_pre + 64, 64);
    k_prep_bn<<<4, 64, 0, stream>>>(bn_add, sc_add, bi_add, 256);
    k_prep_bn<<<4, 64, 0, stream>>>(bn_post, sc_post, bi_post, 256);

    // weight reorder + BN-scale fold
    k_reorder_w1<<<256, 256, 0, stream>>>(w_res, wres, sc_res, 256, 65536);
    k_reorder_w3<<<576, 256, 0, stream>>>(w_vpre, wpre, sc_pre, 256, 128, 0, 147456);
    k_reorder_w3<<<576, 256, 0, stream>>>(w_hpre, wpre, sc_pre + 64, 256, 128, 64, 147456);
    k_reorder_w3<<<576, 256, 0, stream>>>(w_add, wadd, sc_add, 64, 256, 0, 147456);
    k_reorder_w3<<<2304, 256, 0, stream>>>(w_post, wpost, sc_post, 256, 256, 0, 589824);

    // x -> NHWC bf16
    k_cast_x<<<dim3(8, 128, 8), 256, 0, stream>>>(x, xb);

    // res = conv1x1(x)*s + b -> resb
    conv1x1<<<dim3(1024, 2), 256, 0, stream>>>(xb, wres, bi_res, resb);
    // fused vpre+hpre: relu(conv3x3(x)) -> p1 (co 0..63), p2 (co 64..127)
    conv3x3<256, 128, 1><<<dim3(512, 1), 256, 0, stream>>>(xb, wpre, bi_pre, p1, nullptr, p2);
    // pools: p1 = TopPool(p1); p2 = LeftPool(p2) + p1
    k_pool1<<<256, 256, 0, stream>>>(p1);
    k_pool2<<<256, 256, 0, stream>>>(p2, p1);
    // merged + res, relu -> xb
    conv3x3<64, 256, 2><<<dim3(512, 2), 256, 0, stream>>>(p2, wadd, bi_add, xb, resb, nullptr);
    // post conv: relu -> d_out fp32 NCHW
    conv3x3<256, 256, 3><<<dim3(512, 2), 256, 0, stream>>>(xb, wpost, bi_post, d_out, nullptr, nullptr);
}

// Round 18
// 374.076 us; speedup vs baseline: 1.0209x; 1.0209x over previous
//
#include <hip/hip_runtime.h>
#include <hip/hip_bf16.h>

// CornerPool on MI355X, round 20: REVERT to round 15 -- the best measured
// configuration (374.4us total; MODE3 138.2us, MfmaUtil 48%).
// r19's 2-blocks/CU variant was null-to-negative (381.9us): two resident
// blocks stage in lockstep (2.69 vs 2.0 TB/s moved in identical time ->
// stage is latency-exposure-bound, not bandwidth-bound; co-residency can't
// antiphase it). Counted-vmcnt hiding is environmentally unmeasurable
// (3/3 pod deaths). Three decompositions all plateau at MODE3=138us, so
// this locks in the optimum: dw-grouped taps (LDS-read reuse), zero-staging
// global_load_lds with granule rotation, XCD-decorrelated chunk stagger.

using bf16x8  = __attribute__((ext_vector_type(8))) __bf16;
using floatx4 = __attribute__((ext_vector_type(4))) float;

typedef __attribute__((address_space(1))) const uint32_t gas_u32;
typedef __attribute__((address_space(3))) uint32_t las_u32;

__device__ __forceinline__ float bf2f(__hip_bfloat16 h) { return __bfloat162float(h); }
__device__ __forceinline__ __hip_bfloat16 f2bf(float f) { return __float2bfloat16(f); }

// ---------------- prep kernels ----------------

// x: [8][256][128][128] fp32 NCHW -> xb: [8][128][128][256] bf16 NHWC
__global__ __launch_bounds__(256) void k_cast_x(const float* __restrict__ x,
                                                __hip_bfloat16* __restrict__ xb) {
    __shared__ float t[64][65];
    const int n  = blockIdx.z;
    const int h  = blockIdx.y;
    const int c0 = (blockIdx.x >> 1) * 64;
    const int w0 = (blockIdx.x & 1) * 64;
    const int tid = threadIdx.x;
#pragma unroll
    for (int it = 0; it < 16; ++it) {
        int idx = it * 256 + tid;
        int c = idx >> 6, w = idx & 63;
        t[c][w] = x[(((size_t)n * 256 + c0 + c) * 128 + h) * 128 + w0 + w];
    }
    __syncthreads();
#pragma unroll
    for (int it = 0; it < 16; ++it) {
        int idx = it * 256 + tid;
        int w = idx >> 6, c = idx & 63;
        xb[(((size_t)n * 128 + h) * 128 + w0 + w) * 256 + c0 + c] = f2bf(t[c][w]);
    }
}

// bn params [4][C] -> scale[C], bias[C]
__global__ void k_prep_bn(const float* __restrict__ p, float* __restrict__ sc,
                          float* __restrict__ bi, int C) {
    int i = blockIdx.x * 64 + threadIdx.x;
    if (i >= C) return;
    float g = p[i], b = p[C + i], m = p[2 * C + i], v = p[3 * C + i];
    float s = g / sqrtf(v + 1e-5f);
    sc[i] = s;
    bi[i] = b - m * s;
}

// 3x3: src fp32 [CoS][Cin][3][3] -> dst bf16 [tap][Cin/32][CoutTot][32] at co_off
__global__ void k_reorder_w3(const float* __restrict__ src, __hip_bfloat16* __restrict__ dst,
                             const float* __restrict__ scale, int Cin, int CoutTot,
                             int co_off, int total) {
    int i = blockIdx.x * 256 + threadIdx.x;
    if (i >= total) return;
    int ci  = i % Cin;
    int tap = (i / Cin) % 9;
    int co  = i / (Cin * 9);
    dst[((((size_t)tap * (Cin >> 5) + (ci >> 5)) * CoutTot) + co_off + co) * 32 + (ci & 31)] =
        f2bf(src[((size_t)co * Cin + ci) * 9 + tap] * scale[co]);
}

// 1x1: src fp32 [Co][Cin] -> dst bf16 [Co][Cin], scaled
__global__ void k_reorder_w1(const float* __restrict__ src, __hip_bfloat16* __restrict__ dst,
                             const float* __restrict__ scale, int Cin, int total) {
    int i = blockIdx.x * 256 + threadIdx.x;
    if (i >= total) return;
    dst[i] = f2bf(src[i] * scale[i / Cin]);
}

// ---------------- pools (NHWC bf16, C=64, in-place) ----------------

__global__ __launch_bounds__(256) void k_pool1(__hip_bfloat16* __restrict__ b) {
    const int idx = blockIdx.x * 256 + threadIdx.x; // 8*128*64 = 65536
    const int c = idx & 63;
    const int w = (idx >> 6) & 127;
    const int n = idx >> 13;
    const size_t stride = 128 * 64;
    const size_t base = ((size_t)n * 128 * 128 + w) * 64 + c;
    float m = 0.0f; // post-relu inputs are >= 0
    for (int hb = 31; hb >= 0; --hb) {
        size_t a0 = base + (size_t)(4 * hb) * stride;
        float v0 = bf2f(b[a0]);
        float v1 = bf2f(b[a0 + stride]);
        float v2 = bf2f(b[a0 + 2 * stride]);
        float v3 = bf2f(b[a0 + 3 * stride]);
        float m3 = fmaxf(m, v3);
        float m2 = fmaxf(m3, v2);
        float m1 = fmaxf(m2, v1);
        float m0 = fmaxf(m1, v0);
        b[a0 + 3 * stride] = f2bf(m3);
        b[a0 + 2 * stride] = f2bf(m2);
        b[a0 + stride]     = f2bf(m1);
        b[a0]              = f2bf(m0);
        m = m0;
    }
}

__global__ __launch_bounds__(256) void k_pool2(__hip_bfloat16* __restrict__ b,
                                               const __hip_bfloat16* __restrict__ pl) {
    const int idx = blockIdx.x * 256 + threadIdx.x;
    const int c = idx & 63;
    const int h = (idx >> 6) & 127;
    const int n = idx >> 13;
    const size_t base = (((size_t)n * 128 + h) * 128) * 64 + c;
    float m = 0.0f;
    for (int wb = 31; wb >= 0; --wb) {
        size_t a0 = base + (size_t)(4 * wb) * 64;
        float v0 = bf2f(b[a0]);
        float v1 = bf2f(b[a0 + 64]);
        float v2 = bf2f(b[a0 + 128]);
        float v3 = bf2f(b[a0 + 192]);
        float u0 = bf2f(pl[a0]);
        float u1 = bf2f(pl[a0 + 64]);
        float u2 = bf2f(pl[a0 + 128]);
        float u3 = bf2f(pl[a0 + 192]);
        float m3 = fmaxf(m, v3);
        float m2 = fmaxf(m3, v2);
        float m1 = fmaxf(m2, v1);
        float m0 = fmaxf(m1, v0);
        b[a0 + 192] = f2bf(m3 + u3);
        b[a0 + 128] = f2bf(m2 + u2);
        b[a0 + 64]  = f2bf(m1 + u1);
        b[a0]       = f2bf(m0 + u0);
        m = m0;
    }
}

// ---------------- 1x1 conv (res branch): GEMM 16384x256x256 ----------------
__global__ __launch_bounds__(256) void conv1x1(const __hip_bfloat16* __restrict__ xin,
                                               const __hip_bfloat16* __restrict__ wgt,
                                               const float* __restrict__ bias,
                                               __hip_bfloat16* __restrict__ out) {
    __shared__ __align__(16) __hip_bfloat16 Xs[128 * 64];
    __shared__ __align__(16) __hip_bfloat16 Ws[128 * 64];
    const int tid  = threadIdx.x;
    const int lane = tid & 63;
    const int wid  = tid >> 6;
    const int wm = wid >> 1, wn = wid & 1;
    const int p0 = blockIdx.x * 128;
    const int c0 = blockIdx.y * 128;
    const int q = lane >> 4, r16 = lane & 15;

    floatx4 acc[4][4] = {};

    for (int k0 = 0; k0 < 256; k0 += 64) {
#pragma unroll
        for (int it = 0; it < 4; ++it) {
            const int pp = it * 32 + (tid >> 3);
            const int g  = tid & 7;
            uint4 val = *(const uint4*)(xin + ((size_t)(p0 + pp) * 256 + k0 + g * 8));
            *(uint4*)(&Xs[pp * 64 + (((g + pp) & 7) * 8)]) = val;
        }
#pragma unroll
        for (int it = 0; it < 4; ++it) {
            const int rr = it * 32 + (tid >> 3);
            const int g  = tid & 7;
            uint4 val = *(const uint4*)(wgt + ((size_t)(c0 + rr) * 256 + k0 + g * 8));
            *(uint4*)(&Ws[rr * 64 + (((g + rr) & 7) * 8)]) = val;
        }
        __syncthreads();
#pragma unroll
        for (int ks = 0; ks < 2; ++ks) {
            bf16x8 afr[4], bfr[4];
#pragma unroll
            for (int i = 0; i < 4; ++i) {
                const int pp = wm * 64 + i * 16 + r16;
                const int g  = ks * 4 + q;
                afr[i] = *(const bf16x8*)(&Xs[pp * 64 + (((g + pp) & 7) * 8)]);
            }
#pragma unroll
            for (int j = 0; j < 4; ++j) {
                const int rr = wn * 64 + j * 16 + r16;
                const int g  = ks * 4 + q;
                bfr[j] = *(const bf16x8*)(&Ws[rr * 64 + (((g + rr) & 7) * 8)]);
            }
#pragma unroll
            for (int i = 0; i < 4; ++i)
#pragma unroll
                for (int j = 0; j < 4; ++j)
                    acc[i][j] = __builtin_amdgcn_mfma_f32_16x16x32_bf16(afr[i], bfr[j], acc[i][j], 0, 0, 0);
        }
        __syncthreads();
    }
#pragma unroll
    for (int j = 0; j < 4; ++j) {
        const int co = c0 + wn * 64 + j * 16 + r16;
        const float bi = bias[co];
#pragma unroll
        for (int i = 0; i < 4; ++i) {
            const int pb = p0 + wm * 64 + i * 16 + q * 4;
#pragma unroll
            for (int r = 0; r < 4; ++r)
                out[(size_t)(pb + r) * 256 + co] = f2bf(acc[i][j][r] + bi);
        }
    }
}

// ---------------- dw-grouped multi-row 3x3 conv, XCD-decorrelated stagger ----------------
// Block: 4 image rows x 128 w x 128 co. 512 threads, 8 waves.
// LDS: Xs[6][130][32] (49.9KB) + Ws[9][128][32] (73.7KB) = 123.6KB, single-
// buffered, filled ONLY by global_load_lds. Chunk loop (r7/r11 skeleton):
// dw-grouped taps -> barrier -> 15 gll -> barrier. Stagger offset is
// (bx >> 3) % NCH: workgroups land on XCDs round-robin (bx % 8), so bx>>3
// varies WITHIN an XCD -> the 32 CUs of each XCD spread over all chunk
// offsets (4 CUs per W slice in the private L2 instead of 32).
// MODE 1: +relu -> split bf16 NHWC out/out2 (co<64 -> out, else out2), COUT=128
// MODE 2: +bias +res, relu -> bf16 NHWC out, COUT=256
// MODE 3: +relu -> fp32 NCHW out (swapped operands, D[co][p]), COUT=256
template <int CIN, int COUT, int MODE>
__global__ __launch_bounds__(512, 2) void conv3x3(const __hip_bfloat16* __restrict__ xin,
                                                  const __hip_bfloat16* __restrict__ wgt,
                                                  const float* __restrict__ bias,
                                                  void* __restrict__ out,
                                                  const __hip_bfloat16* __restrict__ resbuf,
                                                  __hip_bfloat16* __restrict__ out2) {
    constexpr int NCH = CIN / 32;
    __shared__ __align__(16) __hip_bfloat16 Xs[6 * 130 * 32]; // 49,920 B
    __shared__ __align__(16) __hip_bfloat16 Ws[9 * 128 * 32]; // 73,728 B
    const int tid  = threadIdx.x;
    const int lane = tid & 63;
    const int wid  = tid >> 6;        // 0..7
    const int wm   = wid >> 1;        // 0..3: w-dim, 32 each
    const int wn   = wid & 1;         // 0..1: co, 64 each
    const int bx   = blockIdx.x;      // 0..255
    const int n     = bx >> 5;        // image
    const int hbase = (bx & 31) * 4;  // first output row
    const int co_off = blockIdx.y * 128;
    const int q = lane >> 4, r16 = lane & 15;

    // staging lane decomposition (16B granules)
    const int le = lane >> 2, lp = lane & 3;
    // X: this lane's e-slot and the SOURCE ci-group carrying the inverse rotation
    const int xe = wid * 16 + 1 + le;                  // 1..128
    const int xg = (lp - ((xe >> 1) & 3)) & 3;
    const int xlaneoff = (xe - 1) * CIN + xg * 8;      // element offset, chunk-invariant
    // W: this lane's co-row and inverse-rotated source ci-group
    const int wrow = wid * 16 + le;                    // 0..127
    const int wg2 = (lp - ((wrow >> 1) & 3)) & 3;
    const int wlaneoff = wrow * 32 + wg2 * 8;

    floatx4 acc[4][2][4] = {};

    auto stage = [&](int c) {
        const int ci0 = c * 32;
#pragma unroll
        for (int r = 0; r < 6; ++r) {
            const int hh = hbase - 1 + r;               // wave-uniform
            if (0 <= hh && hh < 128) {
                const __hip_bfloat16* src =
                    xin + ((size_t)(n * 128 + hh) * 128) * CIN + ci0 + xlaneoff;
                __builtin_amdgcn_global_load_lds((gas_u32*)src,
                    (las_u32*)&Xs[((size_t)r * 130 + wid * 16 + 1) * 32], 16, 0, 0);
            } else {
                *(uint4*)(&Xs[((size_t)r * 130 + xe) * 32 + lp * 8]) =
                    make_uint4(0u, 0u, 0u, 0u);
            }
        }
#pragma unroll
        for (int tap = 0; tap < 9; ++tap) {
            const __hip_bfloat16* src =
                wgt + ((size_t)(tap * NCH + c) * COUT + co_off) * 32 + wlaneoff;
            __builtin_amdgcn_global_load_lds((gas_u32*)src,
                (las_u32*)&Ws[((size_t)tap * 128 + wid * 16) * 32], 16, 0, 0);
        }
    };

    // zero halo columns e=0,129 (all 4 granules, 6 rows) -- never re-written
    if (tid < 48) {
        int r = tid >> 3, side = (tid >> 2) & 1, p = tid & 3;
        *(uint4*)(&Xs[((size_t)r * 130 + (side ? 129 : 0)) * 32 + p * 8]) =
            make_uint4(0u, 0u, 0u, 0u);
    }
    // XCD-decorrelated chunk stagger: same-XCD blocks share bx%8, so use
    // bx>>3 to spread the 32 CUs of each XCD over all NCH offsets.
    const int off = (bx >> 3) % NCH;
    stage(off);
    __syncthreads(); // drains gll (compiler emits vmcnt(0) before s_barrier)

    for (int c = 0; c < NCH; ++c) {
        // dw-grouped taps: tap = tr*3 + dwg, dw = dwg-1
#pragma unroll
        for (int dwg = 0; dwg < 3; ++dwg) {
            const int dw = dwg - 1;
            // B fragments for the 3 taps of this dw-group (hoisted across i)
            bf16x8 bfr[3][4];
#pragma unroll
            for (int tr = 0; tr < 3; ++tr)
#pragma unroll
                for (int j = 0; j < 4; ++j) {
                    const int row = wn * 64 + j * 16 + r16;
                    const int pg  = (q + ((row >> 1) & 3)) & 3;
                    bfr[tr][j] = *(const bf16x8*)(
                        &Ws[((size_t)(tr * 3 + dwg) * 128 + row) * 32 + pg * 8]);
                }
#pragma unroll
            for (int i = 0; i < 2; ++i) {
                // A fragments: 6 halo rows at this (i, dw) -- serve all 3 taps
                const int e  = wm * 32 + i * 16 + r16 + dw + 1; // 0..129
                const int pg = (q + ((e >> 1) & 3)) & 3;
                bf16x8 afr[6];
#pragma unroll
                for (int rr = 0; rr < 6; ++rr)
                    afr[rr] = *(const bf16x8*)(
                        &Xs[((size_t)rr * 130 + e) * 32 + pg * 8]);
#pragma unroll
                for (int tr = 0; tr < 3; ++tr)
#pragma unroll
                    for (int row = 0; row < 4; ++row)
#pragma unroll
                        for (int j = 0; j < 4; ++j) {
                            if (MODE == 3)
                                acc[row][i][j] = __builtin_amdgcn_mfma_f32_16x16x32_bf16(
                                    bfr[tr][j], afr[row + tr], acc[row][i][j], 0, 0, 0);
                            else
                                acc[row][i][j] = __builtin_amdgcn_mfma_f32_16x16x32_bf16(
                                    afr[row + tr], bfr[tr][j], acc[row][i][j], 0, 0, 0);
                        }
            }
        }
        __syncthreads(); // all waves done reading this chunk
        if (c + 1 < NCH) {
            stage((c + 1 + off) % NCH);
            __syncthreads(); // DMA drained, LDS holds next chunk
        }
    }

    if (MODE == 1) {
#pragma unroll
        for (int row = 0; row < 4; ++row) {
            const int h = hbase + row;
#pragma unroll
            for (int j = 0; j < 4; ++j) {
                const int co = wn * 64 + j * 16 + r16; // 0..127
                const float bi = bias[co];
                __hip_bfloat16* ob = (co < 64) ? (__hip_bfloat16*)out : out2;
                const int ch = co & 63;
#pragma unroll
                for (int i = 0; i < 2; ++i) {
#pragma unroll
                    for (int r = 0; r < 4; ++r) {
                        const int w = wm * 32 + i * 16 + q * 4 + r;
                        const size_t p = (size_t)(n * 128 + h) * 128 + w;
                        ob[p * 64 + ch] = f2bf(fmaxf(acc[row][i][j][r] + bi, 0.0f));
                    }
                }
            }
        }
    } else if (MODE == 2) {
        __hip_bfloat16* o = (__hip_bfloat16*)out;
#pragma unroll
        for (int row = 0; row < 4; ++row) {
            const int h = hbase + row;
#pragma unroll
            for (int j = 0; j < 4; ++j) {
                const int co = co_off + wn * 64 + j * 16 + r16;
                const float bi = bias[co];
#pragma unroll
                for (int i = 0; i < 2; ++i) {
#pragma unroll
                    for (int r = 0; r < 4; ++r) {
                        const int w = wm * 32 + i * 16 + q * 4 + r;
                        const size_t p = (size_t)(n * 128 + h) * 128 + w;
                        float v = acc[row][i][j][r] + bi + bf2f(resbuf[p * 256 + co]);
                        o[p * 256 + co] = f2bf(fmaxf(v, 0.0f));
                    }
                }
            }
        }
    } else { // MODE 3: fp32 NCHW, D[co][w]
        float* o = (float*)out;
#pragma unroll
        for (int row = 0; row < 4; ++row) {
            const int h = hbase + row;
#pragma unroll
            for (int j = 0; j < 4; ++j) {
#pragma unroll
                for (int r = 0; r < 4; ++r) {
                    const int co = co_off + wn * 64 + j * 16 + q * 4 + r;
                    const float bi = bias[co];
#pragma unroll
                    for (int i = 0; i < 2; ++i) {
                        const int w = wm * 32 + i * 16 + r16;
                        float v = fmaxf(acc[row][i][j][r] + bi, 0.0f);
                        o[(((size_t)(n * 256 + co)) * 128 + h) * 128 + w] = v;
                    }
                }
            }
        }
    }
}

// ---------------- launcher ----------------

extern "C" void kernel_launch(void* const* d_in, const int* in_sizes, int n_in,
                              void* d_out, int out_size, void* d_ws, size_t ws_size,
                              hipStream_t stream) {
    const float* x       = (const float*)d_in[0];
    const float* w_res   = (const float*)d_in[1];
    const float* bn_res  = (const float*)d_in[2];
    const float* w_vpre  = (const float*)d_in[3];
    const float* bn_vpre = (const float*)d_in[4];
    const float* w_hpre  = (const float*)d_in[5];
    const float* bn_hpre = (const float*)d_in[6];
    const float* w_add   = (const float*)d_in[7];
    const float* bn_add  = (const float*)d_in[8];
    const float* w_post  = (const float*)d_in[9];
    const float* bn_post = (const float*)d_in[10];

    const size_t SZ_XB = (size_t)8 * 128 * 128 * 256 * 2; // 67,108,864
    const size_t SZ_P  = (size_t)8 * 128 * 128 * 64 * 2;  // 16,777,216

    char* w = (char*)d_ws;
    __hip_bfloat16* xb   = (__hip_bfloat16*)(w);          // reused as add-conv output
    __hip_bfloat16* resb = (__hip_bfloat16*)(w + SZ_XB);
    __hip_bfloat16* p1   = (__hip_bfloat16*)(w + 2 * SZ_XB);
    __hip_bfloat16* p2   = (__hip_bfloat16*)(w + 2 * SZ_XB + SZ_P);
    char* wp = w + 2 * SZ_XB + 2 * SZ_P;
    __hip_bfloat16* wres  = (__hip_bfloat16*)wp; wp += (size_t)65536 * 2;        // [256][256]
    __hip_bfloat16* wpre  = (__hip_bfloat16*)wp; wp += (size_t)9 * 128 * 256 * 2; // [9][8][128][32]
    __hip_bfloat16* wadd  = (__hip_bfloat16*)wp; wp += (size_t)9 * 256 * 64 * 2;  // [9][2][256][32]
    __hip_bfloat16* wpost = (__hip_bfloat16*)wp; wp += (size_t)9 * 256 * 256 * 2; // [9][8][256][32]
    float* sc_res  = (float*)wp; wp += 256 * 4;
    float* bi_res  = (float*)wp; wp += 256 * 4;
    float* sc_pre  = (float*)wp; wp += 128 * 4;
    float* bi_pre  = (float*)wp; wp += 128 * 4;
    float* sc_add  = (float*)wp; wp += 256 * 4;
    float* bi_add  = (float*)wp; wp += 256 * 4;
    float* sc_post = (float*)wp; wp += 256 * 4;
    float* bi_post = (float*)wp; wp += 256 * 4;

    // BN prep first (reorder kernels consume the scales)
    k_prep_bn<<<4, 64, 0, stream>>>(bn_res, sc_res, bi_res, 256);
    k_prep_bn<<<1, 64, 0, stream>>>(bn_vpre, sc_pre, bi_pre, 64);
    k_prep_bn<<<1, 64, 0, stream>>>(bn_hpre, sc_pre + 64, bi_pre + 64, 64);
    k_prep_bn<<<4, 64, 0, stream>>>(bn_add, sc_add, bi_add, 256);
    k_prep_bn<<<4, 64, 0, stream>>>(bn_post, sc_post, bi_post, 256);

    // weight reorder + BN-scale fold
    k_reorder_w1<<<256, 256, 0, stream>>>(w_res, wres, sc_res, 256, 65536);
    k_reorder_w3<<<576, 256, 0, stream>>>(w_vpre, wpre, sc_pre, 256, 128, 0, 147456);
    k_reorder_w3<<<576, 256, 0, stream>>>(w_hpre, wpre, sc_pre + 64, 256, 128, 64, 147456);
    k_reorder_w3<<<576, 256, 0, stream>>>(w_add, wadd, sc_add, 64, 256, 0, 147456);
    k_reorder_w3<<<2304, 256, 0, stream>>>(w_post, wpost, sc_post, 256, 256, 0, 589824);

    // x -> NHWC bf16
    k_cast_x<<<dim3(8, 128, 8), 256, 0, stream>>>(x, xb);

    // res = conv1x1(x)*s + b -> resb
    conv1x1<<<dim3(1024, 2), 256, 0, stream>>>(xb, wres, bi_res, resb);
    // fused vpre+hpre: relu(conv3x3(x)) -> p1 (co 0..63), p2 (co 64..127)
    conv3x3<256, 128, 1><<<dim3(256, 1), 512, 0, stream>>>(xb, wpre, bi_pre, p1, nullptr, p2);
    // pools: p1 = TopPool(p1); p2 = LeftPool(p2) + p1
    k_pool1<<<256, 256, 0, stream>>>(p1);
    k_pool2<<<256, 256, 0, stream>>>(p2, p1);
    // merged + res, relu -> xb
    conv3x3<64, 256, 2><<<dim3(256, 2), 512, 0, stream>>>(p2, wadd, bi_add, xb, resb, nullptr);
    // post conv: relu -> d_out fp32 NCHW
    conv3x3<256, 256, 3><<<dim3(256, 2), 512, 0, stream>>>(xb, wpost, bi_post, d_out, nullptr, nullptr);
}